// Round 4
// baseline (509.237 us; speedup 1.0000x reference)
//
#include <hip/hip_runtime.h>
#include <hip/hip_cooperative_groups.h>
#include <hip/hip_bf16.h>
#include <math.h>

#define S_LEN 4096
#define NH    8

typedef __attribute__((ext_vector_type(8))) short bf16x8;
typedef __attribute__((ext_vector_type(4))) short bf16x4;
typedef __attribute__((ext_vector_type(4))) float f32x4;
typedef __attribute__((ext_vector_type(16))) float f32x16;
typedef __attribute__((ext_vector_type(2)))  int   int32x2;
typedef __attribute__((ext_vector_type(4)))  unsigned short u16x4;

#define QSCALE 0.18033688011112042f   // 0.125 * log2(e): scores land in exp2 domain

// s_waitcnt imm (gfx9 encoding): vmcnt[3:0], expcnt=7 (dc), lgkmcnt=15 (dc)
#define WAIT_VM6 0x0F76
#define WAIT_VM4 0x0F74
#define WAIT_VM0 0x0F70

// fp32 -> bf16 round-to-nearest-even (scalar)
__device__ __forceinline__ short f2bf(float f) {
    union { float f; unsigned u; } v; v.f = f;
    unsigned r = v.u + 0x7fffu + ((v.u >> 16) & 1u);
    return (short)(r >> 16);
}

__device__ __forceinline__ float bf2f(unsigned short s) {
    union { unsigned u; float f; } v; v.u = ((unsigned)s) << 16; return v.f;
}

// packed 2x fp32 -> bf16 (v_cvt_pk_bf16_f32 on gfx950)
__device__ __forceinline__ int pk2(float a, float b) {
    __hip_bfloat162 t = __float22bfloat162_rn(make_float2(a, b));
    union { __hip_bfloat162 h; int i; } u; u.h = t;
    return u.i;
}

// async 16B global->LDS; HW writes lane i's 16B to ldsbase + i*16
__device__ __forceinline__ void gload16(const void* g, void* l) {
    __builtin_amdgcn_global_load_lds(
        (const __attribute__((address_space(1))) unsigned*)g,
        (__attribute__((address_space(3))) unsigned*)l, 16, 0, 0);
}

// ---------------------------------------------------------------------------
// Stage a 64x64 bf16 tile into an 8KB LDS tile with XOR-swizzled 16B column
// groups: phys(row, cg) = row*128B + ((cg ^ (row&7)) * 16B). Swizzle applied
// on the GLOBAL source address so wave-uniform-base global_load_lds lands
// data where frag() expects.  2 loads per wave per tile.
// ---------------------------------------------------------------------------
__device__ __forceinline__ void stage_tile(const short* gsrc, size_t gstride,
                                           short* tile, int t)
{
    const int wave = t >> 6, lane = t & 63;
    const int sub = lane >> 3;
    const int cg  = (lane & 7) ^ sub;
#pragma unroll
    for (int j = 0; j < 2; ++j) {
        const int chunk = wave * 2 + j;
        const int row = chunk * 8 + sub;
        gload16(gsrc + (size_t)row * gstride + cg * 8, tile + chunk * 512);
    }
}

__device__ __forceinline__ bf16x8 frag(const short* tile, int row, int cg) {
    return *(const bf16x8*)&tile[row * 64 + ((cg ^ (row & 7)) << 3)];
}

// ---------------------------------------------------------------------------
// T12: build the PV B-fragment for key group kc fully in registers.
// r = permlane32_swap(we, wo):
//   r[0]=new_we = [h0: own we ; h1: partner wo]   -> w0/w1
//   r[1]=new_wo = [h0: partner we ; h1: own wo]   -> w2/w3
// Row-sum (l) folded in as f32 lane-local accumulation (pre-rounding).
// ---------------------------------------------------------------------------
__device__ __forceinline__ bf16x8 mk_bp(const f32x16& sc, const int p, float& lsum)
{
    const float e0 = __builtin_amdgcn_exp2f(sc[8 * p + 0]);
    const float e1 = __builtin_amdgcn_exp2f(sc[8 * p + 1]);
    const float e2 = __builtin_amdgcn_exp2f(sc[8 * p + 2]);
    const float e3 = __builtin_amdgcn_exp2f(sc[8 * p + 3]);
    const float e4 = __builtin_amdgcn_exp2f(sc[8 * p + 4]);
    const float e5 = __builtin_amdgcn_exp2f(sc[8 * p + 5]);
    const float e6 = __builtin_amdgcn_exp2f(sc[8 * p + 6]);
    const float e7 = __builtin_amdgcn_exp2f(sc[8 * p + 7]);
    lsum += ((e0 + e1) + (e2 + e3)) + ((e4 + e5) + (e6 + e7));
    int we0 = pk2(e0, e1), we1 = pk2(e2, e3);
    int wo0 = pk2(e4, e5), wo1 = pk2(e6, e7);
    const int32x2 r0 = __builtin_amdgcn_permlane32_swap(we0, wo0, false, false);
    const int32x2 r1 = __builtin_amdgcn_permlane32_swap(we1, wo1, false, false);
    union { int i[4]; bf16x8 v; } u;
    u.i[0] = r0[0]; u.i[1] = r1[0]; u.i[2] = r0[1]; u.i[3] = r1[1];
    return u.v;
}

// ---------------------------------------------------------------------------
// 64x64-tile MFMA GEMM mainloop, K=512 (used by out phase), double-buffered
// global_load_lds with RAW-BARRIER pipeline (no vmcnt(0) drain in-loop).
// ---------------------------------------------------------------------------
__device__ __forceinline__ void gemm_mainloop_512(
    const short* __restrict__ Arow, const short* __restrict__ Brow,
    short* As, short* Bs, f32x4 acc[4], int t)
{
    const int wave = t >> 6, lane = t & 63, n16 = lane & 15, quad = lane >> 4;
    stage_tile(Arow, 512, As, t);
    stage_tile(Brow, 512, Bs, t);
    for (int c = 0; c < 8; ++c) {
        const int cur = c & 1;
        __builtin_amdgcn_s_barrier();                  // A
        if (c < 7) {
            stage_tile(Arow + (c + 1) * 64, 512, As + (1 - cur) * 4096, t);
            stage_tile(Brow + (c + 1) * 64, 512, Bs + (1 - cur) * 4096, t);
            __builtin_amdgcn_s_waitcnt(WAIT_VM4);
        } else {
            __builtin_amdgcn_s_waitcnt(WAIT_VM0);
        }
        __builtin_amdgcn_s_barrier();                  // B
        const short* as = As + cur * 4096;
        const short* bs = Bs + cur * 4096;
#pragma unroll
        for (int kh = 0; kh < 2; ++kh) {
            const bf16x8 a = frag(as, wave * 16 + n16, kh * 4 + quad);
#pragma unroll
            for (int nt = 0; nt < 4; ++nt) {
                const bf16x8 b = frag(bs, nt * 16 + n16, kh * 4 + quad);
                acc[nt] = __builtin_amdgcn_mfma_f32_16x16x32_bf16(a, b, acc[nt], 0, 0, 0);
            }
        }
    }
}

// ---------------------------------------------------------------------------
// Phase bodies (shared by the fused cooperative kernel and the fallback
// standalone kernels).
// ---------------------------------------------------------------------------
__device__ __forceinline__ void prep_body(
    int b, int t, short* T,
    const float* __restrict__ x,
    const float* __restrict__ Wq, const float* __restrict__ Wk,
    const float* __restrict__ Wv, const float* __restrict__ Wo,
    short* __restrict__ xb, short* __restrict__ Wqkvt, short* __restrict__ Wot)
{
    if (b < 1024) {
        const size_t idx = (size_t)b * 2048 + t * 8;
        const float4 a = *(const float4*)&x[idx];
        const float4 c = *(const float4*)&x[idx + 4];
        bf16x8 o;
        o[0] = f2bf(a.x); o[1] = f2bf(a.y); o[2] = f2bf(a.z); o[3] = f2bf(a.w);
        o[4] = f2bf(c.x); o[5] = f2bf(c.y); o[6] = f2bf(c.z); o[7] = f2bf(c.w);
        *(bf16x8*)&xb[idx] = o;
        return;
    }
    const int c4 = (t & 15) * 4, rsub = t >> 4;
    const int orow = t >> 2, oc16 = (t & 3) * 16;
    if (b < 1216) {
        const int jj = b - 1024, g = jj >> 3, kb = jj & 7;
        const int which = g >> 3, h = g & 7;
        const float* W = ((which == 0) ? Wq : (which == 1) ? Wk : Wv) + (size_t)h * 512 * 64;
#pragma unroll
        for (int p = 0; p < 4; ++p) {
            const int row = p * 16 + rsub;
            const float4 v = *(const float4*)&W[(size_t)(kb * 64 + row) * 64 + c4];
            T[(c4 + 0) * 66 + row] = f2bf(v.x);
            T[(c4 + 1) * 66 + row] = f2bf(v.y);
            T[(c4 + 2) * 66 + row] = f2bf(v.z);
            T[(c4 + 3) * 66 + row] = f2bf(v.w);
        }
        __syncthreads();
        short* O = &Wqkvt[((size_t)g * 64 + orow) * 512 + kb * 64];
        *(bf16x8*)&O[oc16]     = *(const bf16x8*)&T[orow * 66 + oc16];
        *(bf16x8*)&O[oc16 + 8] = *(const bf16x8*)&T[orow * 66 + oc16 + 8];
    } else {
        const int jj = b - 1216, h = jj >> 3, nb = jj & 7;
        const float* W = Wo + (size_t)h * 64 * 512;
#pragma unroll
        for (int p = 0; p < 4; ++p) {
            const int row = p * 16 + rsub;
            const float4 v = *(const float4*)&W[(size_t)row * 512 + nb * 64 + c4];
            T[(c4 + 0) * 66 + row] = f2bf(v.x);
            T[(c4 + 1) * 66 + row] = f2bf(v.y);
            T[(c4 + 2) * 66 + row] = f2bf(v.z);
            T[(c4 + 3) * 66 + row] = f2bf(v.w);
        }
        __syncthreads();
        short* O = &Wot[((size_t)nb * 64 + orow) * 512 + h * 64];
        *(bf16x8*)&O[oc16]     = *(const bf16x8*)&T[orow * 66 + oc16];
        *(bf16x8*)&O[oc16 + 8] = *(const bf16x8*)&T[orow * 66 + oc16 + 8];
    }
}

// QKV projection, BM=128 x BN=64 tile. Q pre-scaled by QSCALE; Q,K stored
// [h][s][64]; V stored transposed [h][d][s] via LDS bounce.
__device__ __forceinline__ void qkv_body(
    int sblk, int g, int t, short* smem,
    const short* __restrict__ xb, const short* __restrict__ Wqkvt,
    short* __restrict__ Qg, short* __restrict__ Kg, short* __restrict__ Vtg)
{
    short* As = smem;                      // 2 x 8192
    short* Bs = smem + 16384;              // 2 x 4096
    const int which = g >> 3, h = g & 7;
    const int wave = t >> 6, lane = t & 63, n16 = lane & 15, quad = lane >> 4;

    const short* Arow = xb + (size_t)sblk * 128 * 512;
    const short* Brow = Wqkvt + (size_t)g * 64 * 512;

    f32x4 acc[2][4] = {{{0,0,0,0},{0,0,0,0},{0,0,0,0},{0,0,0,0}},
                       {{0,0,0,0},{0,0,0,0},{0,0,0,0},{0,0,0,0}}};

    stage_tile(Arow,            512, As,        t);
    stage_tile(Arow + 64 * 512, 512, As + 4096, t);
    stage_tile(Brow,            512, Bs,        t);
    for (int c = 0; c < 8; ++c) {
        const int cur = c & 1;
        __builtin_amdgcn_s_barrier();                  // A
        if (c < 7) {
            stage_tile(Arow + (c + 1) * 64,            512, As + (1 - cur) * 8192,        t);
            stage_tile(Arow + 64 * 512 + (c + 1) * 64, 512, As + (1 - cur) * 8192 + 4096, t);
            stage_tile(Brow + (c + 1) * 64,            512, Bs + (1 - cur) * 4096,        t);
            __builtin_amdgcn_s_waitcnt(WAIT_VM6);
        } else {
            __builtin_amdgcn_s_waitcnt(WAIT_VM0);
        }
        __builtin_amdgcn_s_barrier();                  // B
        const short* as = As + cur * 8192;
        const short* bs = Bs + cur * 4096;
        const int r0 = wave * 32 + n16;
        const short* a_sub = as + (r0 >> 6) * 4096;
#pragma unroll
        for (int kh = 0; kh < 2; ++kh) {
            const bf16x8 a0 = frag(a_sub, r0 & 63,        kh * 4 + quad);
            const bf16x8 a1 = frag(a_sub, (r0 & 63) + 16, kh * 4 + quad);
#pragma unroll
            for (int nt = 0; nt < 4; ++nt) {
                const bf16x8 b = frag(bs, nt * 16 + n16, kh * 4 + quad);
                acc[0][nt] = __builtin_amdgcn_mfma_f32_16x16x32_bf16(a0, b, acc[0][nt], 0, 0, 0);
                acc[1][nt] = __builtin_amdgcn_mfma_f32_16x16x32_bf16(a1, b, acc[1][nt], 0, 0, 0);
            }
        }
    }

    if (which < 2) {
        const float scale = (which == 0) ? QSCALE : 1.0f;
        short* O = ((which == 0) ? Qg : Kg) + (size_t)h * S_LEN * 64;
#pragma unroll
        for (int m = 0; m < 2; ++m)
#pragma unroll
            for (int nt = 0; nt < 4; ++nt)
#pragma unroll
                for (int r = 0; r < 4; ++r) {
                    const int s = sblk * 128 + wave * 32 + m * 16 + quad * 4 + r;
                    O[(size_t)s * 64 + nt * 16 + n16] = f2bf(acc[m][nt][r] * scale);
                }
    } else {
        __syncthreads();                   // all waves done with smem
        short* Tr = smem;                  // 64 x 130 transpose bounce
#pragma unroll
        for (int m = 0; m < 2; ++m)
#pragma unroll
            for (int nt = 0; nt < 4; ++nt)
#pragma unroll
                for (int r = 0; r < 4; ++r)
                    Tr[(nt * 16 + n16) * 130 + wave * 32 + m * 16 + quad * 4 + r] =
                        f2bf(acc[m][nt][r]);
        __syncthreads();
        short* O = Vtg + (size_t)h * 64 * S_LEN + sblk * 128;
        const int vr = t >> 2, c32 = (t & 3) * 32;
#pragma unroll
        for (int u = 0; u < 4; ++u)
            *(bf16x8*)&O[(size_t)vr * S_LEN + c32 + u * 8] =
                *(const bf16x8*)&Tr[vr * 130 + c32 + u * 8];
    }
}

// Flash attention chunk (causal, static-reference softmax p=exp2(sc)).
// smem layout: K dbuf at [0,8192), V dbuf at [8192,16384) shorts.
__device__ __forceinline__ void attn_body(
    int id, int t, short* smem,
    const short* __restrict__ Qg, const short* __restrict__ Kg,
    const short* __restrict__ Vtg, short* __restrict__ Opart,
    float* __restrict__ Lpart)
{
    const int h  = id & 7;
    const int c  = 79 - (id >> 3);         // longest chunks first
    int qs, j;
    if (c < 8)       { qs = c;                   j = 0; }
    else if (c < 24) { qs = 8 + ((c - 8) >> 1);  j = (c - 8) & 1; }
    else if (c < 48) { qs = 16 + (c - 24) / 3;   j = (c - 24) % 3; }
    else             { qs = 24 + ((c - 48) >> 2); j = (c - 48) & 3; }
    const int k0   = j * 16;
    const int kend = min(k0 + 16, 2 * qs + 2);

    const short* Kh  = Kg  + (size_t)h * S_LEN * 64;
    const short* Vth = Vtg + (size_t)h * 64 * S_LEN;

    const int wave = t >> 6, lane = t & 63, l31 = lane & 31, half = lane >> 5;
    const int qg = qs * 128 + wave * 32 + l31;   // this lane's global q

    const short* Qr = Qg + (size_t)h * S_LEN * 64 + (size_t)qg * 64;
    bf16x8 bq[4];
#pragma unroll
    for (int kc = 0; kc < 4; ++kc)
        bq[kc] = *(const bf16x8*)&Qr[kc * 16 + half * 8];

    f32x16 z16;
#pragma unroll
    for (int r = 0; r < 16; ++r) z16[r] = 0.f;

    f32x16 oacc[2];
#pragma unroll
    for (int r = 0; r < 16; ++r) { oacc[0][r] = 0.f; oacc[1][r] = 0.f; }
    float llane = 0.f;

    stage_tile(Kh + (size_t)k0 * 64 * 64, 64, smem, t);
    stage_tile(Vth + k0 * 64, S_LEN, smem + 8192, t);

    for (int kb = k0; kb < kend; ++kb) {
        const int cur = (kb - k0) & 1;
        const short* Kc = smem + cur * 4096;
        const short* Vc = smem + 8192 + cur * 4096;
        __builtin_amdgcn_s_barrier();                  // A: buf^1 free
        if (kb + 1 < kend) {
            stage_tile(Kh + (size_t)(kb + 1) * 64 * 64, 64, smem + (1 - cur) * 4096, t);
            stage_tile(Vth + (kb + 1) * 64, S_LEN, smem + 8192 + (1 - cur) * 4096, t);
            __builtin_amdgcn_s_waitcnt(WAIT_VM4);
        } else {
            __builtin_amdgcn_s_waitcnt(WAIT_VM0);
        }
        __builtin_amdgcn_s_barrier();                  // B: buf cur ready

        __builtin_amdgcn_s_setprio(1);
        f32x16 sc0, sc1;
        {
            const bf16x8 a0 = frag(Kc, l31,      half);
            const bf16x8 a1 = frag(Kc, 32 + l31, half);
            sc0 = __builtin_amdgcn_mfma_f32_32x32x16_bf16(a0, bq[0], z16, 0, 0, 0);
            sc1 = __builtin_amdgcn_mfma_f32_32x32x16_bf16(a1, bq[0], z16, 0, 0, 0);
        }
#pragma unroll
        for (int kc = 1; kc < 4; ++kc) {
            const bf16x8 a0 = frag(Kc, l31,      kc * 2 + half);
            const bf16x8 a1 = frag(Kc, 32 + l31, kc * 2 + half);
            sc0 = __builtin_amdgcn_mfma_f32_32x32x16_bf16(a0, bq[kc], sc0, 0, 0, 0);
            sc1 = __builtin_amdgcn_mfma_f32_32x32x16_bf16(a1, bq[kc], sc1, 0, 0, 0);
        }
        __builtin_amdgcn_s_setprio(0);

        if (kb * 64 + 63 > qg) {
#pragma unroll
            for (int r = 0; r < 16; ++r) {
                const int keyb = kb * 64 + (r & 3) + 8 * (r >> 2) + 4 * half;
                if (keyb > qg)      sc0[r] = -1e30f;
                if (keyb + 32 > qg) sc1[r] = -1e30f;
            }
        }

        bf16x8 bp[4];
        bp[0] = mk_bp(sc0, 0, llane);
        bp[1] = mk_bp(sc0, 1, llane);
        bp[2] = mk_bp(sc1, 0, llane);
        bp[3] = mk_bp(sc1, 1, llane);

        __builtin_amdgcn_s_setprio(1);
#pragma unroll
        for (int kc = 0; kc < 4; ++kc) {
            const bf16x8 a0 = frag(Vc, l31,      kc * 2 + half);
            const bf16x8 a1 = frag(Vc, 32 + l31, kc * 2 + half);
            oacc[0] = __builtin_amdgcn_mfma_f32_32x32x16_bf16(a0, bp[kc], oacc[0], 0, 0, 0);
            oacc[1] = __builtin_amdgcn_mfma_f32_32x32x16_bf16(a1, bp[kc], oacc[1], 0, 0, 0);
        }
        __builtin_amdgcn_s_setprio(0);
    }

    short* tileO = Opart + (size_t)(h * 80 + c) * (64 * 128);
    float* tileL = Lpart + (h * 80 + c) * 128;
    const float lq = llane + __shfl_xor(llane, 32, 64);
    if (half == 0) tileL[wave * 32 + l31] = lq;
#pragma unroll
    for (int mt = 0; mt < 2; ++mt)
#pragma unroll
        for (int r = 0; r < 16; ++r) {
            const int v = mt * 32 + (r & 3) + 8 * (r >> 2) + 4 * half;
            tileO[(v << 7) + wave * 32 + l31] = f2bf(mt ? oacc[1][r] : oacc[0][r]);
        }
}

// Combine partials + normalize + transpose -> vals[s][h*64+v] bf16.
__device__ __forceinline__ void combine_body(
    int id, int t, short* T,
    const short* __restrict__ Opart, const float* __restrict__ Lpart,
    short* __restrict__ vals)
{
    const int h = id & 7, qs = id >> 3;
    int c0, nj;
    if (qs < 8)       { c0 = qs;                 nj = 1; }
    else if (qs < 16) { c0 = 8 + 2 * (qs - 8);   nj = 2; }
    else if (qs < 24) { c0 = 24 + 3 * (qs - 16); nj = 3; }
    else              { c0 = 48 + 4 * (qs - 24); nj = 4; }
    const int base = h * 80 + c0;

    const int q0 = (t & 31) * 4;
    const int vr = t >> 5;

    f32x4 L = {0, 0, 0, 0};
    for (int j = 0; j < nj; ++j)
        L += *(const f32x4*)&Lpart[(base + j) * 128 + q0];
    const f32x4 inv = {1.f / L[0], 1.f / L[1], 1.f / L[2], 1.f / L[3]};

#pragma unroll
    for (int pass = 0; pass < 8; ++pass) {
        const int v = vr + pass * 8;
        f32x4 s = {0, 0, 0, 0};
        for (int j = 0; j < nj; ++j) {
            const u16x4 u = *(const u16x4*)&Opart[(size_t)(base + j) * 8192 + (v << 7) + q0];
            s[0] += bf2f(u[0]); s[1] += bf2f(u[1]);
            s[2] += bf2f(u[2]); s[3] += bf2f(u[3]);
        }
        T[(q0 + 0) * 66 + v] = f2bf(s[0] * inv[0]);
        T[(q0 + 1) * 66 + v] = f2bf(s[1] * inv[1]);
        T[(q0 + 2) * 66 + v] = f2bf(s[2] * inv[2]);
        T[(q0 + 3) * 66 + v] = f2bf(s[3] * inv[3]);
    }
    __syncthreads();
    const int q = t >> 1, vh = (t & 1) * 32;
    const size_t row = (size_t)(qs * 128 + q) * 512 + h * 64 + vh;
#pragma unroll
    for (int u = 0; u < 4; ++u)
        *(bf16x8*)&vals[row + u * 8] = *(const bf16x8*)&T[q * 66 + vh + u * 8];
}

// Output projection: vals bf16 [4096][512] x Wot[n][c] -> out fp32.
__device__ __forceinline__ void out_body(
    int sblk, int g, int t, short* smem,
    const short* __restrict__ vals, const short* __restrict__ Wot,
    float* __restrict__ out)
{
    short* As = smem;
    short* Bs = smem + 8192;
    const int wave = t >> 6, lane = t & 63, n16 = lane & 15, quad = lane >> 4;

    f32x4 acc[4] = {{0,0,0,0},{0,0,0,0},{0,0,0,0},{0,0,0,0}};
    gemm_mainloop_512(vals + (size_t)sblk * 64 * 512, Wot + (size_t)g * 64 * 512,
                      As, Bs, acc, t);

#pragma unroll
    for (int nt = 0; nt < 4; ++nt)
#pragma unroll
        for (int r = 0; r < 4; ++r) {
            const int s = sblk * 64 + wave * 16 + quad * 4 + r;
            out[(size_t)s * 512 + g * 64 + nt * 16 + n16] = acc[nt][r];
        }
}

// ---------------------------------------------------------------------------
// Fused cooperative kernel: all 5 phases, 4 grid syncs, grid = 768 blocks
// (= 256 CU x 3 resident at 48KB LDS / (256,3)).  Eliminates 4 dispatch
// boundaries (launch gap + wave ramp/drain each).
// ---------------------------------------------------------------------------
__global__ __launch_bounds__(256, 3) void fused_kernel(
    const float* __restrict__ x,
    const float* __restrict__ Wq, const float* __restrict__ Wk,
    const float* __restrict__ Wv, const float* __restrict__ Wo,
    float* __restrict__ out,
    short* __restrict__ xb, short* __restrict__ Wqkvt, short* __restrict__ Wot,
    short* __restrict__ Qg, short* __restrict__ Kg, short* __restrict__ Vtg,
    short* __restrict__ vals, short* __restrict__ Opart, float* __restrict__ Lpart)
{
    cooperative_groups::grid_group grid = cooperative_groups::this_grid();
    __shared__ short smem[24576];          // 48 KB, unioned across phases
    const int bid = blockIdx.x, t = threadIdx.x;

    // phase 1: prep (1280 units, <=2 per block; LDS units land 1-per-block)
    for (int u = bid; u < 1280; u += 768)
        prep_body(u, t, smem, x, Wq, Wk, Wv, Wo, xb, Wqkvt, Wot);
    grid.sync();

    // phase 2: qkv (768 units, 1:1)
    qkv_body(bid & 31, bid >> 5, t, smem, xb, Wqkvt, Qg, Kg, Vtg);
    grid.sync();

    // phase 3: attention (640 chunks; all co-resident -> longest chunk bounds)
    if (bid < 640) attn_body(bid, t, smem, Qg, Kg, Vtg, Opart, Lpart);
    grid.sync();

    // phase 4: combine partials (256 units)
    if (bid < 256) combine_body(bid, t, smem, Opart, Lpart, vals);
    grid.sync();

    // phase 5: output projection (512 units)
    if (bid < 512) out_body(bid & 63, bid >> 6, t, smem, vals, Wot, out);
}

// ---------------------------------------------------------------------------
// Fallback standalone kernels (used only if cooperative launch fails).
// ---------------------------------------------------------------------------
__global__ __launch_bounds__(256) void prep_kernel(
    const float* __restrict__ x,
    const float* __restrict__ Wq, const float* __restrict__ Wk,
    const float* __restrict__ Wv, const float* __restrict__ Wo,
    short* __restrict__ xb, short* __restrict__ Wqkvt, short* __restrict__ Wot)
{
    __shared__ short T[64 * 66];
    prep_body(blockIdx.x, threadIdx.x, T, x, Wq, Wk, Wv, Wo, xb, Wqkvt, Wot);
}

__global__ __launch_bounds__(256) void qkv_gemm_kernel(
    const short* __restrict__ xb, const short* __restrict__ Wqkvt,
    short* __restrict__ Qg, short* __restrict__ Kg, short* __restrict__ Vtg)
{
    __shared__ short smem[24576];
    qkv_body(blockIdx.x, blockIdx.y, threadIdx.x, smem, xb, Wqkvt, Qg, Kg, Vtg);
}

__global__ __launch_bounds__(256, 3) void attn_kernel(
    const short* __restrict__ Qg, const short* __restrict__ Kg,
    const short* __restrict__ Vtg, short* __restrict__ Opart, float* __restrict__ Lpart)
{
    __shared__ short smem[16384];
    attn_body(blockIdx.x, threadIdx.x, smem, Qg, Kg, Vtg, Opart, Lpart);
}

__global__ __launch_bounds__(256) void combine_norm_kernel(
    const short* __restrict__ Opart, const float* __restrict__ Lpart,
    short* __restrict__ vals)
{
    __shared__ short T[128 * 66];
    combine_body(blockIdx.x, threadIdx.x, T, Opart, Lpart, vals);
}

__global__ __launch_bounds__(256) void out_gemm_kernel(
    const short* __restrict__ vals, const short* __restrict__ Wot, float* __restrict__ out)
{
    __shared__ short smem[16384];
    out_body(blockIdx.x, blockIdx.y, threadIdx.x, smem, vals, Wot, out);
}

// ---------------------------------------------------------------------------
// Workspace: shorts (xb | Wqkvt | Wot | Qg | Kg | Vtg | vals | Opart bf16),
// then fp32 Lpart 640x128  ~= 33 MB total.
// ---------------------------------------------------------------------------
extern "C" void kernel_launch(void* const* d_in, const int* in_sizes, int n_in,
                              void* d_out, int out_size, void* d_ws, size_t ws_size,
                              hipStream_t stream)
{
    const float* x  = (const float*)d_in[0];
    const float* Wq = (const float*)d_in[1];
    const float* Wk = (const float*)d_in[2];
    const float* Wv = (const float*)d_in[3];
    const float* Wo = (const float*)d_in[4];
    float* out = (float*)d_out;

    short* xb    = (short*)d_ws;
    short* Wqkvt = xb + 2097152;
    short* Wot   = Wqkvt + 786432;
    short* Qg    = Wot + 262144;
    short* Kg    = Qg + 2097152;
    short* Vtg   = Kg + 2097152;
    short* vals  = Vtg + 2097152;
    short* Opart = vals + 2097152;
    float* Lpart = (float*)(Opart + (size_t)640 * 8192);

    void* args[] = {(void*)&x, (void*)&Wq, (void*)&Wk, (void*)&Wv, (void*)&Wo,
                    (void*)&out, (void*)&xb, (void*)&Wqkvt, (void*)&Wot,
                    (void*)&Qg, (void*)&Kg, (void*)&Vtg, (void*)&vals,
                    (void*)&Opart, (void*)&Lpart};
    const hipError_t e = hipLaunchCooperativeKernel(
        (void*)fused_kernel, dim3(768), dim3(256), args, 0, stream);
    if (e != hipSuccess) {
        (void)hipGetLastError();           // clear sticky error, use fallback
        prep_kernel<<<1280, 256, 0, stream>>>(x, Wq, Wk, Wv, Wo, xb, Wqkvt, Wot);
        qkv_gemm_kernel<<<dim3(32, 24), 256, 0, stream>>>(xb, Wqkvt, Qg, Kg, Vtg);
        attn_kernel<<<640, 256, 0, stream>>>(Qg, Kg, Vtg, Opart, Lpart);
        combine_norm_kernel<<<256, 256, 0, stream>>>(Opart, Lpart, vals);
        out_gemm_kernel<<<dim3(64, 8), 256, 0, stream>>>(vals, Wot, out);
    }
}

// Round 5
// 133.130 us; speedup vs baseline: 3.8251x; 3.8251x over previous
//
#include <hip/hip_runtime.h>
#include <hip/hip_bf16.h>
#include <math.h>

#define S_LEN 4096
#define NH    8

typedef __attribute__((ext_vector_type(8))) short bf16x8;
typedef __attribute__((ext_vector_type(4))) short bf16x4;
typedef __attribute__((ext_vector_type(4))) float f32x4;
typedef __attribute__((ext_vector_type(16))) float f32x16;
typedef __attribute__((ext_vector_type(2)))  int   int32x2;
typedef __attribute__((ext_vector_type(4)))  unsigned short u16x4;

#define QSCALE 0.18033688011112042f   // 0.125 * log2(e): scores land in exp2 domain

// s_waitcnt imm (gfx9 encoding): vmcnt[3:0], expcnt=7 (dc), lgkmcnt=15 (dc)
#define WAIT_VM6 0x0F76
#define WAIT_VM4 0x0F74
#define WAIT_VM0 0x0F70

// fp32 -> bf16 round-to-nearest-even (scalar)
__device__ __forceinline__ short f2bf(float f) {
    union { float f; unsigned u; } v; v.f = f;
    unsigned r = v.u + 0x7fffu + ((v.u >> 16) & 1u);
    return (short)(r >> 16);
}

__device__ __forceinline__ float bf2f(unsigned short s) {
    union { unsigned u; float f; } v; v.u = ((unsigned)s) << 16; return v.f;
}

// packed 2x fp32 -> bf16 (v_cvt_pk_bf16_f32 on gfx950)
__device__ __forceinline__ int pk2(float a, float b) {
    __hip_bfloat162 t = __float22bfloat162_rn(make_float2(a, b));
    union { __hip_bfloat162 h; int i; } u; u.h = t;
    return u.i;
}

// async 16B global->LDS; HW writes lane i's 16B to ldsbase + i*16
__device__ __forceinline__ void gload16(const void* g, void* l) {
    __builtin_amdgcn_global_load_lds(
        (const __attribute__((address_space(1))) unsigned*)g,
        (__attribute__((address_space(3))) unsigned*)l, 16, 0, 0);
}

// ---------------------------------------------------------------------------
// Stage a 64x64 bf16 tile into an 8KB LDS tile with XOR-swizzled 16B column
// groups: phys(row, cg) = row*128B + ((cg ^ (row&7)) * 16B). Swizzle applied
// on the GLOBAL source address so wave-uniform-base global_load_lds lands
// data where frag() expects.  2 loads per wave per tile.
// ---------------------------------------------------------------------------
__device__ __forceinline__ void stage_tile(const short* gsrc, size_t gstride,
                                           short* tile, int t)
{
    const int wave = t >> 6, lane = t & 63;
    const int sub = lane >> 3;
    const int cg  = (lane & 7) ^ sub;
#pragma unroll
    for (int j = 0; j < 2; ++j) {
        const int chunk = wave * 2 + j;
        const int row = chunk * 8 + sub;
        gload16(gsrc + (size_t)row * gstride + cg * 8, tile + chunk * 512);
    }
}

__device__ __forceinline__ bf16x8 frag(const short* tile, int row, int cg) {
    return *(const bf16x8*)&tile[row * 64 + ((cg ^ (row & 7)) << 3)];
}

// ---------------------------------------------------------------------------
// T12: build the PV B-fragment for key group kc fully in registers.
// r = permlane32_swap(we, wo):
//   r[0]=new_we = [h0: own we ; h1: partner wo]   -> w0/w1
//   r[1]=new_wo = [h0: partner we ; h1: own wo]   -> w2/w3
// Row-sum (l) folded in as f32 lane-local accumulation (pre-rounding).
// ---------------------------------------------------------------------------
__device__ __forceinline__ bf16x8 mk_bp(const f32x16& sc, const int p, float& lsum)
{
    const float e0 = __builtin_amdgcn_exp2f(sc[8 * p + 0]);
    const float e1 = __builtin_amdgcn_exp2f(sc[8 * p + 1]);
    const float e2 = __builtin_amdgcn_exp2f(sc[8 * p + 2]);
    const float e3 = __builtin_amdgcn_exp2f(sc[8 * p + 3]);
    const float e4 = __builtin_amdgcn_exp2f(sc[8 * p + 4]);
    const float e5 = __builtin_amdgcn_exp2f(sc[8 * p + 5]);
    const float e6 = __builtin_amdgcn_exp2f(sc[8 * p + 6]);
    const float e7 = __builtin_amdgcn_exp2f(sc[8 * p + 7]);
    lsum += ((e0 + e1) + (e2 + e3)) + ((e4 + e5) + (e6 + e7));
    int we0 = pk2(e0, e1), we1 = pk2(e2, e3);
    int wo0 = pk2(e4, e5), wo1 = pk2(e6, e7);
    const int32x2 r0 = __builtin_amdgcn_permlane32_swap(we0, wo0, false, false);
    const int32x2 r1 = __builtin_amdgcn_permlane32_swap(we1, wo1, false, false);
    union { int i[4]; bf16x8 v; } u;
    u.i[0] = r0[0]; u.i[1] = r1[0]; u.i[2] = r0[1]; u.i[3] = r1[1];
    return u.v;
}

// ---------------------------------------------------------------------------
// 64x64-tile MFMA GEMM mainloop, K=512 (used by out_gemm), double-buffered
// global_load_lds with RAW-BARRIER pipeline (no vmcnt(0) drain in-loop).
// ---------------------------------------------------------------------------
__device__ __forceinline__ void gemm_mainloop_512(
    const short* __restrict__ Arow, const short* __restrict__ Brow,
    short* As, short* Bs, f32x4 acc[4], int t)
{
    const int wave = t >> 6, lane = t & 63, n16 = lane & 15, quad = lane >> 4;
    stage_tile(Arow, 512, As, t);
    stage_tile(Brow, 512, Bs, t);
    for (int c = 0; c < 8; ++c) {
        const int cur = c & 1;
        __builtin_amdgcn_s_barrier();                  // A
        if (c < 7) {
            stage_tile(Arow + (c + 1) * 64, 512, As + (1 - cur) * 4096, t);
            stage_tile(Brow + (c + 1) * 64, 512, Bs + (1 - cur) * 4096, t);
            __builtin_amdgcn_s_waitcnt(WAIT_VM4);
        } else {
            __builtin_amdgcn_s_waitcnt(WAIT_VM0);
        }
        __builtin_amdgcn_s_barrier();                  // B
        const short* as = As + cur * 4096;
        const short* bs = Bs + cur * 4096;
#pragma unroll
        for (int kh = 0; kh < 2; ++kh) {
            const bf16x8 a = frag(as, wave * 16 + n16, kh * 4 + quad);
#pragma unroll
            for (int nt = 0; nt < 4; ++nt) {
                const bf16x8 b = frag(bs, nt * 16 + n16, kh * 4 + quad);
                acc[nt] = __builtin_amdgcn_mfma_f32_16x16x32_bf16(a, b, acc[nt], 0, 0, 0);
            }
        }
    }
}

// ---------------------------------------------------------------------------
// Prep: x->bf16; weight transposes via coalesced LDS tiles.
// ---------------------------------------------------------------------------
__global__ __launch_bounds__(256) void prep_kernel(
    const float* __restrict__ x,
    const float* __restrict__ Wq, const float* __restrict__ Wk,
    const float* __restrict__ Wv, const float* __restrict__ Wo,
    short* __restrict__ xb, short* __restrict__ Wqkvt, short* __restrict__ Wot)
{
    __shared__ short T[64 * 66];
    const int b = blockIdx.x, t = threadIdx.x;
    if (b < 1024) {
        const size_t idx = (size_t)b * 2048 + t * 8;
        const float4 a = *(const float4*)&x[idx];
        const float4 c = *(const float4*)&x[idx + 4];
        bf16x8 o;
        o[0] = f2bf(a.x); o[1] = f2bf(a.y); o[2] = f2bf(a.z); o[3] = f2bf(a.w);
        o[4] = f2bf(c.x); o[5] = f2bf(c.y); o[6] = f2bf(c.z); o[7] = f2bf(c.w);
        *(bf16x8*)&xb[idx] = o;
        return;
    }
    const int c4 = (t & 15) * 4, rsub = t >> 4;
    const int orow = t >> 2, oc16 = (t & 3) * 16;
    if (b < 1216) {
        const int jj = b - 1024, g = jj >> 3, kb = jj & 7;
        const int which = g >> 3, h = g & 7;
        const float* W = ((which == 0) ? Wq : (which == 1) ? Wk : Wv) + (size_t)h * 512 * 64;
#pragma unroll
        for (int p = 0; p < 4; ++p) {
            const int row = p * 16 + rsub;
            const float4 v = *(const float4*)&W[(size_t)(kb * 64 + row) * 64 + c4];
            T[(c4 + 0) * 66 + row] = f2bf(v.x);
            T[(c4 + 1) * 66 + row] = f2bf(v.y);
            T[(c4 + 2) * 66 + row] = f2bf(v.z);
            T[(c4 + 3) * 66 + row] = f2bf(v.w);
        }
        __syncthreads();
        short* O = &Wqkvt[((size_t)g * 64 + orow) * 512 + kb * 64];
        *(bf16x8*)&O[oc16]     = *(const bf16x8*)&T[orow * 66 + oc16];
        *(bf16x8*)&O[oc16 + 8] = *(const bf16x8*)&T[orow * 66 + oc16 + 8];
    } else {
        const int jj = b - 1216, h = jj >> 3, nb = jj & 7;
        const float* W = Wo + (size_t)h * 64 * 512;
#pragma unroll
        for (int p = 0; p < 4; ++p) {
            const int row = p * 16 + rsub;
            const float4 v = *(const float4*)&W[(size_t)row * 512 + nb * 64 + c4];
            T[(c4 + 0) * 66 + row] = f2bf(v.x);
            T[(c4 + 1) * 66 + row] = f2bf(v.y);
            T[(c4 + 2) * 66 + row] = f2bf(v.z);
            T[(c4 + 3) * 66 + row] = f2bf(v.w);
        }
        __syncthreads();
        short* O = &Wot[((size_t)nb * 64 + orow) * 512 + h * 64];
        *(bf16x8*)&O[oc16]     = *(const bf16x8*)&T[orow * 66 + oc16];
        *(bf16x8*)&O[oc16 + 8] = *(const bf16x8*)&T[orow * 66 + oc16 + 8];
    }
}

// ---------------------------------------------------------------------------
// QKV projection, BM=128 x BN=64 tiles. Q pre-scaled by QSCALE; Q,K stored
// [h][s][64]; V stored transposed [h][d][s] via LDS bounce.
// ---------------------------------------------------------------------------
__global__ __launch_bounds__(256) void qkv_gemm_kernel(
    const short* __restrict__ xb, const short* __restrict__ Wqkvt,
    short* __restrict__ Qg, short* __restrict__ Kg, short* __restrict__ Vtg)
{
    __shared__ short smem[24576];          // As 2x8192 | Bs 2x4096 (48 KB)
    short* As = smem;
    short* Bs = smem + 16384;
    const int sblk = blockIdx.x, g = blockIdx.y;
    const int which = g >> 3, h = g & 7;
    const int t = threadIdx.x;
    const int wave = t >> 6, lane = t & 63, n16 = lane & 15, quad = lane >> 4;

    const short* Arow = xb + (size_t)sblk * 128 * 512;
    const short* Brow = Wqkvt + (size_t)g * 64 * 512;

    f32x4 acc[2][4] = {{{0,0,0,0},{0,0,0,0},{0,0,0,0},{0,0,0,0}},
                       {{0,0,0,0},{0,0,0,0},{0,0,0,0},{0,0,0,0}}};

    stage_tile(Arow,            512, As,        t);
    stage_tile(Arow + 64 * 512, 512, As + 4096, t);
    stage_tile(Brow,            512, Bs,        t);
    for (int c = 0; c < 8; ++c) {
        const int cur = c & 1;
        __builtin_amdgcn_s_barrier();                  // A
        if (c < 7) {
            stage_tile(Arow + (c + 1) * 64,            512, As + (1 - cur) * 8192,        t);
            stage_tile(Arow + 64 * 512 + (c + 1) * 64, 512, As + (1 - cur) * 8192 + 4096, t);
            stage_tile(Brow + (c + 1) * 64,            512, Bs + (1 - cur) * 4096,        t);
            __builtin_amdgcn_s_waitcnt(WAIT_VM6);
        } else {
            __builtin_amdgcn_s_waitcnt(WAIT_VM0);
        }
        __builtin_amdgcn_s_barrier();                  // B
        const short* as = As + cur * 8192;
        const short* bs = Bs + cur * 4096;
        const int r0 = wave * 32 + n16;
        const short* a_sub = as + (r0 >> 6) * 4096;
#pragma unroll
        for (int kh = 0; kh < 2; ++kh) {
            const bf16x8 a0 = frag(a_sub, r0 & 63,        kh * 4 + quad);
            const bf16x8 a1 = frag(a_sub, (r0 & 63) + 16, kh * 4 + quad);
#pragma unroll
            for (int nt = 0; nt < 4; ++nt) {
                const bf16x8 b = frag(bs, nt * 16 + n16, kh * 4 + quad);
                acc[0][nt] = __builtin_amdgcn_mfma_f32_16x16x32_bf16(a0, b, acc[0][nt], 0, 0, 0);
                acc[1][nt] = __builtin_amdgcn_mfma_f32_16x16x32_bf16(a1, b, acc[1][nt], 0, 0, 0);
            }
        }
    }

    if (which < 2) {
        const float scale = (which == 0) ? QSCALE : 1.0f;
        short* O = ((which == 0) ? Qg : Kg) + (size_t)h * S_LEN * 64;
#pragma unroll
        for (int m = 0; m < 2; ++m)
#pragma unroll
            for (int nt = 0; nt < 4; ++nt)
#pragma unroll
                for (int r = 0; r < 4; ++r) {
                    const int s = sblk * 128 + wave * 32 + m * 16 + quad * 4 + r;
                    O[(size_t)s * 64 + nt * 16 + n16] = f2bf(acc[m][nt][r] * scale);
                }
    } else {
        __syncthreads();                   // all waves done with smem
        short* Tr = smem;                  // 64 x 130 transpose bounce
#pragma unroll
        for (int m = 0; m < 2; ++m)
#pragma unroll
            for (int nt = 0; nt < 4; ++nt)
#pragma unroll
                for (int r = 0; r < 4; ++r)
                    Tr[(nt * 16 + n16) * 130 + wave * 32 + m * 16 + quad * 4 + r] =
                        f2bf(acc[m][nt][r]);
        __syncthreads();
        short* O = Vtg + (size_t)h * 64 * S_LEN + sblk * 128;
        const int vr = t >> 2, c32 = (t & 3) * 32;
#pragma unroll
        for (int u = 0; u < 4; ++u)
            *(bf16x8*)&O[(size_t)vr * S_LEN + c32 + u * 8] =
                *(const bf16x8*)&Tr[vr * 130 + c32 + u * 8];
    }
}

// ---------------------------------------------------------------------------
// Output projection: vals bf16 [4096][512] x Wot[n][c] -> out fp32.
// ---------------------------------------------------------------------------
__global__ __launch_bounds__(256) void out_gemm_kernel(
    const short* __restrict__ vals, const short* __restrict__ Wot, float* __restrict__ out)
{
    __shared__ short smem[16384];
    short* As = smem;
    short* Bs = smem + 8192;
    const int sblk = blockIdx.x, g = blockIdx.y;
    const int t = threadIdx.x;
    const int wave = t >> 6, lane = t & 63, n16 = lane & 15, quad = lane >> 4;

    f32x4 acc[4] = {{0,0,0,0},{0,0,0,0},{0,0,0,0},{0,0,0,0}};
    gemm_mainloop_512(vals + (size_t)sblk * 64 * 512, Wot + (size_t)g * 64 * 512,
                      As, Bs, acc, t);

#pragma unroll
    for (int nt = 0; nt < 4; ++nt)
#pragma unroll
        for (int r = 0; r < 4; ++r) {
            const int s = sblk * 64 + wave * 16 + quad * 4 + r;
            out[(size_t)s * 512 + g * 64 + nt * 16 + n16] = acc[nt][r];
        }
}

// ---------------------------------------------------------------------------
// Flash attention, causal, static-reference softmax (p = exp2(sc), exact by
// shift-invariance). 32x32x16 MFMA, raw-barrier pipelined staging, T12
// in-register P, T5 setprio.
// Split-k REBALANCED to budget B=13 tiles/chunk: per head, qs0-5->1 chunk,
// qs6-12->2, qs13-18->3, qs19-25->4, qs26-31->5  = 96 chunks x 8 h = 768
// blocks = exactly 256 CU x 3 resident.  Critical path 16->13 steps, slot
// occupancy 640/768 -> 768/768.  Longest chunks dispatched first.
// Partials bf16: Opart[slot][v 64][q 128] + fp32 Lpart[slot][q 128].
// ---------------------------------------------------------------------------
__global__ __launch_bounds__(256, 3) void attn_kernel(
    const short* __restrict__ Qg, const short* __restrict__ Kg,
    const short* __restrict__ Vtg, short* __restrict__ Opart, float* __restrict__ Lpart)
{
    __shared__ short Ks[2][4096];
    __shared__ short Vs[2][4096];

    const int id = blockIdx.x;
    const int h  = id & 7;
    const int cc = 95 - (id >> 3);         // reversed: longest chunks first
    int qs, j;
    if (cc < 6)       { qs = cc;                    j = 0; }
    else if (cc < 20) { qs = 6  + ((cc - 6) >> 1);  j = (cc - 6) & 1; }
    else if (cc < 38) { qs = 13 + (cc - 20) / 3;    j = (cc - 20) % 3; }
    else if (cc < 66) { qs = 19 + ((cc - 38) >> 2); j = (cc - 38) & 3; }
    else              { qs = 26 + (cc - 66) / 5;    j = (cc - 66) % 5; }
    const int k0   = j * 13;
    const int kend = min(k0 + 13, 2 * qs + 2);

    const short* Kh  = Kg  + (size_t)h * S_LEN * 64;
    const short* Vth = Vtg + (size_t)h * 64 * S_LEN;

    const int t = threadIdx.x;
    const int wave = t >> 6, lane = t & 63, l31 = lane & 31, half = lane >> 5;
    const int qg = qs * 128 + wave * 32 + l31;   // this lane's global q

    // Q B-fragments, loop-invariant: B[k=d][n=q] = Q[qg][d]
    const short* Qr = Qg + (size_t)h * S_LEN * 64 + (size_t)qg * 64;
    bf16x8 bq[4];
#pragma unroll
    for (int kc = 0; kc < 4; ++kc)
        bq[kc] = *(const bf16x8*)&Qr[kc * 16 + half * 8];

    // invariant zero C operand for score MFMAs
    f32x16 z16;
#pragma unroll
    for (int r = 0; r < 16; ++r) z16[r] = 0.f;

    f32x16 oacc[2];
#pragma unroll
    for (int r = 0; r < 16; ++r) { oacc[0][r] = 0.f; oacc[1][r] = 0.f; }
    float llane = 0.f;

    stage_tile(Kh + (size_t)k0 * 64 * 64, 64, Ks[0], t);
    stage_tile(Vth + k0 * 64, S_LEN, Vs[0], t);

    for (int kb = k0; kb < kend; ++kb) {
        const int cur = (kb - k0) & 1;
        __builtin_amdgcn_s_barrier();                  // A: buf^1 free to overwrite
        if (kb + 1 < kend) {
            stage_tile(Kh + (size_t)(kb + 1) * 64 * 64, 64, Ks[1 - cur], t);
            stage_tile(Vth + (kb + 1) * 64, S_LEN, Vs[1 - cur], t);
            __builtin_amdgcn_s_waitcnt(WAIT_VM4);      // kb's 4 loads done
        } else {
            __builtin_amdgcn_s_waitcnt(WAIT_VM0);
        }
        __builtin_amdgcn_s_barrier();                  // B: buf cur ready for all

        // Sc^T = K x Q^T  (kc=0 seeds from invariant zero regs)
        __builtin_amdgcn_s_setprio(1);
        f32x16 sc0, sc1;
        {
            const bf16x8 a0 = frag(Ks[cur], l31,      half);
            const bf16x8 a1 = frag(Ks[cur], 32 + l31, half);
            sc0 = __builtin_amdgcn_mfma_f32_32x32x16_bf16(a0, bq[0], z16, 0, 0, 0);
            sc1 = __builtin_amdgcn_mfma_f32_32x32x16_bf16(a1, bq[0], z16, 0, 0, 0);
        }
#pragma unroll
        for (int kc = 1; kc < 4; ++kc) {
            const bf16x8 a0 = frag(Ks[cur], l31,      kc * 2 + half);
            const bf16x8 a1 = frag(Ks[cur], 32 + l31, kc * 2 + half);
            sc0 = __builtin_amdgcn_mfma_f32_32x32x16_bf16(a0, bq[kc], sc0, 0, 0, 0);
            sc1 = __builtin_amdgcn_mfma_f32_32x32x16_bf16(a1, bq[kc], sc1, 0, 0, 0);
        }
        __builtin_amdgcn_s_setprio(0);

        // causal mask: only tiles that straddle the diagonal
        if (kb * 64 + 63 > qg) {
#pragma unroll
            for (int r = 0; r < 16; ++r) {
                const int keyb = kb * 64 + (r & 3) + 8 * (r >> 2) + 4 * half;
                if (keyb > qg)      sc0[r] = -1e30f;
                if (keyb + 32 > qg) sc1[r] = -1e30f;
            }
        }

        // p = exp2(sc): in-register bf16 B-fragments (T12), l folded in
        bf16x8 bp[4];
        bp[0] = mk_bp(sc0, 0, llane);
        bp[1] = mk_bp(sc0, 1, llane);
        bp[2] = mk_bp(sc1, 0, llane);
        bp[3] = mk_bp(sc1, 1, llane);

        // O^T += V^T x P
        __builtin_amdgcn_s_setprio(1);
#pragma unroll
        for (int kc = 0; kc < 4; ++kc) {
            const bf16x8 a0 = frag(Vs[cur], l31,      kc * 2 + half);
            const bf16x8 a1 = frag(Vs[cur], 32 + l31, kc * 2 + half);
            oacc[0] = __builtin_amdgcn_mfma_f32_32x32x16_bf16(a0, bp[kc], oacc[0], 0, 0, 0);
            oacc[1] = __builtin_amdgcn_mfma_f32_32x32x16_bf16(a1, bp[kc], oacc[1], 0, 0, 0);
        }
        __builtin_amdgcn_s_setprio(0);
    }

    // coalesced bf16 partial stores; l[q] = own-half sum + partner-half sum
    short* tileO = Opart + (size_t)(h * 96 + cc) * (64 * 128);
    float* tileL = Lpart + (h * 96 + cc) * 128;
    const float lq = llane + __shfl_xor(llane, 32, 64);
    if (half == 0) tileL[wave * 32 + l31] = lq;
#pragma unroll
    for (int mt = 0; mt < 2; ++mt)
#pragma unroll
        for (int r = 0; r < 16; ++r) {
            const int v = mt * 32 + (r & 3) + 8 * (r >> 2) + 4 * half;
            tileO[(v << 7) + wave * 32 + l31] = f2bf(mt ? oacc[1][r] : oacc[0][r]);
        }
}

// ---------------------------------------------------------------------------
// Combine partials + normalize + transpose -> vals[s][h*64+v] bf16.
// One block per (h, q-super of 128): sum <=5 bf16 slot tiles [v 64][q 128],
// divide by summed l[q], bf16-pack into LDS [q][v] (stride 66), write rows.
// ---------------------------------------------------------------------------
__global__ __launch_bounds__(256) void combine_norm_kernel(
    const short* __restrict__ Opart, const float* __restrict__ Lpart,
    short* __restrict__ vals)
{
    __shared__ short T[128 * 66];
    const int id = blockIdx.x;
    const int h = id & 7, qs = id >> 3;
    int c0, nj;
    if (qs < 6)       { c0 = qs;                 nj = 1; }
    else if (qs < 13) { c0 = 6  + 2 * (qs - 6);  nj = 2; }
    else if (qs < 19) { c0 = 20 + 3 * (qs - 13); nj = 3; }
    else if (qs < 26) { c0 = 38 + 4 * (qs - 19); nj = 4; }
    else              { c0 = 66 + 5 * (qs - 26); nj = 5; }
    const int base = h * 96 + c0;

    const int t = threadIdx.x;
    const int q0 = (t & 31) * 4;
    const int vr = t >> 5;

    f32x4 L = {0, 0, 0, 0};
    for (int j = 0; j < nj; ++j)
        L += *(const f32x4*)&Lpart[(base + j) * 128 + q0];
    const f32x4 inv = {1.f / L[0], 1.f / L[1], 1.f / L[2], 1.f / L[3]};

#pragma unroll
    for (int pass = 0; pass < 8; ++pass) {
        const int v = vr + pass * 8;
        f32x4 s = {0, 0, 0, 0};
        for (int j = 0; j < nj; ++j) {
            const u16x4 u = *(const u16x4*)&Opart[(size_t)(base + j) * 8192 + (v << 7) + q0];
            s[0] += bf2f(u[0]); s[1] += bf2f(u[1]);
            s[2] += bf2f(u[2]); s[3] += bf2f(u[3]);
        }
        T[(q0 + 0) * 66 + v] = f2bf(s[0] * inv[0]);
        T[(q0 + 1) * 66 + v] = f2bf(s[1] * inv[1]);
        T[(q0 + 2) * 66 + v] = f2bf(s[2] * inv[2]);
        T[(q0 + 3) * 66 + v] = f2bf(s[3] * inv[3]);
    }
    __syncthreads();
    const int q = t >> 1, vh = (t & 1) * 32;
    const size_t row = (size_t)(qs * 128 + q) * 512 + h * 64 + vh;
#pragma unroll
    for (int u = 0; u < 4; ++u)
        *(bf16x8*)&vals[row + u * 8] = *(const bf16x8*)&T[q * 66 + vh + u * 8];
}

// ---------------------------------------------------------------------------
// Workspace: shorts (xb | Wqkvt | Wot | Qg | Kg | Vtg | vals | Opart bf16),
// then fp32 Lpart 768x128  ~= 34 MB total.
// ---------------------------------------------------------------------------
extern "C" void kernel_launch(void* const* d_in, const int* in_sizes, int n_in,
                              void* d_out, int out_size, void* d_ws, size_t ws_size,
                              hipStream_t stream)
{
    const float* x  = (const float*)d_in[0];
    const float* Wq = (const float*)d_in[1];
    const float* Wk = (const float*)d_in[2];
    const float* Wv = (const float*)d_in[3];
    const float* Wo = (const float*)d_in[4];
    float* out = (float*)d_out;

    short* xb    = (short*)d_ws;
    short* Wqkvt = xb + 2097152;
    short* Wot   = Wqkvt + 786432;
    short* Qg    = Wot + 262144;
    short* Kg    = Qg + 2097152;
    short* Vtg   = Kg + 2097152;
    short* vals  = Vtg + 2097152;
    short* Opart = vals + 2097152;
    float* Lpart = (float*)(Opart + (size_t)768 * 8192);

    prep_kernel<<<1280, 256, 0, stream>>>(x, Wq, Wk, Wv, Wo, xb, Wqkvt, Wot);
    qkv_gemm_kernel<<<dim3(32, 24), 256, 0, stream>>>(xb, Wqkvt, Qg, Kg, Vtg);
    attn_kernel<<<768, 256, 0, stream>>>(Qg, Kg, Vtg, Opart, Lpart);
    combine_norm_kernel<<<256, 256, 0, stream>>>(Opart, Lpart, vals);
    out_gemm_kernel<<<dim3(64, 8), 256, 0, stream>>>(vals, Wot, out);
}